// Round 5
// baseline (60.572 us; speedup 1.0000x reference)
//
#include <hip/hip_runtime.h>
#include <hip/hip_bf16.h>

// SWA with sinks: B=2, Q=512, HQ=32, HKV=8 (GQA rep=4), D=128, BS=128,
// NBLK=16, MAXK=2048, WIN=1024 (read dynamically). fp32 in/out, bf16 MFMA.
// R5: 32x32x16 MFMA with 32 q-rows/wave (halves per-q LDS read traffic),
// P kept fully in-register via v_permlane32_swap_b32 (no P LDS round trip),
// denom = per-lane partial + 1 epilogue shuffle. 2-wave blocks, grid 512.

#define B_    2
#define Q_    512
#define HQ_   32
#define HKV_  8
#define D_    128
#define BS_   128
#define NBLK_ 16
#define NPHYS (B_*NBLK_)
#define QBLK  64
#define KBLK  64
#define KVROW (HKV_*D_)   // 1024 floats per key position

typedef __attribute__((ext_vector_type(8)))  __bf16 bf16x8;
typedef __attribute__((ext_vector_type(16))) float  f32x16;
typedef __attribute__((ext_vector_type(4)))  float  float4v;
typedef __attribute__((ext_vector_type(4)))  unsigned int u32x4;
typedef __attribute__((ext_vector_type(2)))  unsigned int u32x2;

#if __has_builtin(__builtin_amdgcn_exp2f)
#define EXP2(x) __builtin_amdgcn_exp2f(x)
#else
#define EXP2(x) exp2f(x)
#endif

#define MFMA32(a, b, c) __builtin_amdgcn_mfma_f32_32x32x16_bf16(a, b, c, 0, 0, 0)

// Compiler emits v_cvt_pk_bf16_f32 from paired scalar casts (m240).
__device__ __forceinline__ unsigned pk2(float a, float b) {
    union { __bf16 h[2]; unsigned u; } x;
    x.h[0] = (__bf16)a; x.h[1] = (__bf16)b;
    return x.u;
}

__device__ __forceinline__ void gld16(const void* g, void* l) {
    __builtin_amdgcn_global_load_lds(
        (const __attribute__((address_space(1))) void*)g,
        (__attribute__((address_space(3))) void*)l, 16, 0, 0);
}

// ---------------- pre-pass: fp32 KV -> bf16 ws, relayout ----------------
// wsK: [phys][kh][key 128][d 128] bf16, 256B rows XOR-swizzled byte^=(key&15)<<4
// wsV: [phys][kh][tile 2][kc 4][d 128][k16 16] bf16 (V^T, 32B rows)
// Grid mapping: bid&7 = kh so prepass writes land in the consumer XCD's L2.
__global__ __launch_bounds__(256) void swa_prepass(
    const float* __restrict__ kv,
    unsigned short* __restrict__ wsK,
    unsigned short* __restrict__ wsV)
{
    const int tid  = threadIdx.x;
    const int kh   = blockIdx.x & 7;
    const int rest = blockIdx.x >> 3;
    const int phys = rest >> 1;
    const int part = rest & 1;
    const int pk   = phys * 8 + kh;

    if (part == 0) {
        const int row = tid >> 1;
        const int dh  = (tid & 1) * 64;
        const float* src = kv + ((size_t)(phys * 2 + 0) * BS_ + row) * KVROW + kh * D_ + dh;
        char* dstrow = (char*)(wsK + ((size_t)pk * BS_ + row) * D_);
        const int swz = (row & 15) << 4;
        #pragma unroll
        for (int i = 0; i < 8; ++i) {
            const float4v f0 = *reinterpret_cast<const float4v*>(src + i * 8);
            const float4v f1 = *reinterpret_cast<const float4v*>(src + i * 8 + 4);
            u32x4 p;
            p[0] = pk2(f0[0], f0[1]); p[1] = pk2(f0[2], f0[3]);
            p[2] = pk2(f1[0], f1[1]); p[3] = pk2(f1[2], f1[3]);
            *reinterpret_cast<u32x4*>(dstrow + ((dh * 2 + i * 16) ^ swz)) = p;
        }
    } else {
        const int db  = tid & 31;    // d-block of 4
        const int kb8 = tid >> 5;    // 0..7
        #pragma unroll
        for (int tile = 0; tile < 2; ++tile) {
            unsigned short* dstt = wsV + ((size_t)pk * 2 + tile) * 8192;
            #pragma unroll
            for (int half = 0; half < 2; ++half) {
                const int kb  = kb8 + half * 8;   // 0..15
                const int k0  = kb * 4;           // key within 64-tile
                const int key = tile * 64 + k0;
                const float* vsrc = kv + ((size_t)(phys * 2 + 1) * BS_ + key) * KVROW + kh * D_ + db * 4;
                const float4v r0 = *reinterpret_cast<const float4v*>(vsrc);
                const float4v r1 = *reinterpret_cast<const float4v*>(vsrc + KVROW);
                const float4v r2 = *reinterpret_cast<const float4v*>(vsrc + 2 * KVROW);
                const float4v r3 = *reinterpret_cast<const float4v*>(vsrc + 3 * KVROW);
                #pragma unroll
                for (int dd = 0; dd < 4; ++dd) {
                    const int d    = db * 4 + dd;
                    const int elem = (k0 >> 4) * 2048 + d * 16 + (k0 & 15);
                    u32x2 wv;
                    wv[0] = pk2(r0[dd], r1[dd]);
                    wv[1] = pk2(r2[dd], r3[dd]);
                    *reinterpret_cast<u32x2*>(dstt + elem) = wv;
                }
            }
        }
    }
}

// ---------------- main kernel: 2 waves x 32 q-rows, 32x32x16 MFMA ----------------
__global__ __launch_bounds__(128, 1) void swa_main(
    const float* __restrict__ q,
    const int*   __restrict__ btab,
    const int*   __restrict__ seqused,
    const float* __restrict__ sinks,
    const int*   __restrict__ winp,
    const unsigned short* __restrict__ wsK,
    const unsigned short* __restrict__ wsV,
    float*       __restrict__ out)
{
    __shared__ __align__(16) unsigned short Kb[2][8192];  // [key 64][d 128] swizzled
    __shared__ __align__(16) unsigned short Vb[2][8192];  // [kc 4][d 128][k16]

    const int tid  = threadIdx.x;
    const int lane = tid & 63;
    const int w    = tid >> 6;       // wave 0/1
    const int l31  = lane & 31;
    const int lhi5 = lane >> 5;      // 0/1

    // kh-major block mapping: bid%8 = kh -> same-kh blocks share an XCD L2.
    const int bid   = blockIdx.x;
    const int kh    = bid & 7;
    const int inner = bid >> 3;
    const int qt    = inner & 7;
    const int hr    = (inner >> 3) & 3;
    const int b     = inner >> 5;
    const int h     = kh * 4 + hr;

    const int seq  = seqused[b];
    const int win  = winp[0];
    const int q0   = qt * QBLK;
    const int pos0 = seq - Q_ + q0;

    const int lo  = pos0 - win + 1;
    const int jt0 = (lo < 0 ? 0 : lo) & ~63;
    const int jt1 = (pos0 + QBLK - 1) & ~63;
    const int nt  = ((jt1 - jt0) >> 6) + 1;

    const float SCL2 = 0.08838834764831845f * 1.4426950408889634f;

    // ---- Q fragments: row = q0 + w*32 + l31; qf[c][j] = Q[., c*16 + lhi5*8 + j] ----
    const int    qr    = q0 + w * 32 + l31;
    const size_t qbase = ((size_t)(b * Q_ + qr) * HQ_ + h) * D_;
    bf16x8 qf[8];
    #pragma unroll
    for (int c = 0; c < 8; ++c) {
        const float4v f0 = *reinterpret_cast<const float4v*>(q + qbase + c * 16 + lhi5 * 8);
        const float4v f1 = *reinterpret_cast<const float4v*>(q + qbase + c * 16 + lhi5 * 8 + 4);
        u32x4 p;
        p[0] = pk2(f0[0] * SCL2, f0[1] * SCL2); p[1] = pk2(f0[2] * SCL2, f0[3] * SCL2);
        p[2] = pk2(f1[0] * SCL2, f1[1] * SCL2); p[3] = pk2(f1[2] * SCL2, f1[3] * SCL2);
        qf[c] = __builtin_bit_cast(bf16x8, p);
    }

    const int   pqmin = pos0 + w * 32;
    const int   pqmax = pqmin + 31;
    const int   posq  = pqmin + l31;
    const float sink2 = sinks[h] * 1.4426950408889634f;
    float mrun  = sink2;     // running max (log2 units)
    float lsink = 1.0f;      // running 2^(sink2 - mrun)
    float plsum = 0.0f;      // per-lane partial sum of P
    f32x16 o[4];
    #pragma unroll
    for (int m = 0; m < 4; ++m) o[m] = (f32x16)(0.f);

    // ---- stage tile 0 ----
    {
        const int blk = btab[b * NBLK_ + (jt0 >> 7)];
        const unsigned short* ks = wsK + ((size_t)(blk * 8 + kh) * BS_ + (jt0 & 127)) * D_;
        const unsigned short* vs = wsV + ((size_t)(blk * 8 + kh) * 2 + ((jt0 >> 6) & 1)) * 8192;
        #pragma unroll
        for (int i = 0; i < 8; ++i)
            gld16(ks + (w * 8 + i) * 512 + lane * 8, &Kb[0][(w * 8 + i) * 512]);
        #pragma unroll
        for (int i = 0; i < 8; ++i)
            gld16(vs + (w * 8 + i) * 512 + lane * 8, &Vb[0][(w * 8 + i) * 512]);
    }
    __syncthreads();

    int cur = 0;
    for (int t = 0; t < nt; ++t) {
        const int jt = jt0 + t * KBLK;

        // ---- prefetch next tile into other buffer ----
        if (t + 1 < nt) {
            const int jn  = jt + KBLK;
            const int blk = btab[b * NBLK_ + (jn >> 7)];
            const unsigned short* ks = wsK + ((size_t)(blk * 8 + kh) * BS_ + (jn & 127)) * D_;
            const unsigned short* vs = wsV + ((size_t)(blk * 8 + kh) * 2 + ((jn >> 6) & 1)) * 8192;
            const int nb = cur ^ 1;
            #pragma unroll
            for (int i = 0; i < 8; ++i)
                gld16(ks + (w * 8 + i) * 512 + lane * 8, &Kb[nb][(w * 8 + i) * 512]);
            #pragma unroll
            for (int i = 0; i < 8; ++i)
                gld16(vs + (w * 8 + i) * 512 + lane * 8, &Vb[nb][(w * 8 + i) * 512]);
        }

        // ---- compute (skip if fully masked for this wave) ----
        if (jt <= pqmax && jt + KBLK - 1 > pqmin - win) {
            const bool edge = (jt + KBLK - 1 > pqmin) || (jt <= pqmax - win);

            // ---- S^T = K·Q : 2 m-blocks (32 keys) x 8 d-chunks ----
            f32x16 sacc[2];
            sacc[0] = (f32x16)(0.f);
            sacc[1] = (f32x16)(0.f);
            const char* kbase = (const char*)&Kb[cur][0];
            const int   swz   = (l31 & 15) << 4;
            __builtin_amdgcn_s_setprio(1);
            #pragma unroll
            for (int mb = 0; mb < 2; ++mb) {
                const char* krow = kbase + (mb * 32 + l31) * 256;
                #pragma unroll
                for (int c = 0; c < 8; ++c) {
                    const bf16x8 a = *reinterpret_cast<const bf16x8*>(
                        krow + ((c * 32 + lhi5 * 16) ^ swz));
                    sacc[mb] = MFMA32(a, qf[c], sacc[mb]);
                }
            }
            __builtin_amdgcn_s_setprio(0);

            // ---- masking + per-lane local max (in-place, no cross-lane) ----
            // C layout: col q = l31, row k = mb*32 + (r&3) + 8*(r>>2) + 4*lhi5
            float mloc = -3e38f;
            if (edge) {
                #pragma unroll
                for (int mb = 0; mb < 2; ++mb) {
                    #pragma unroll
                    for (int r = 0; r < 16; ++r) {
                        const int  kglob = jt + mb * 32 + (r & 3) + 8 * (r >> 2) + 4 * lhi5;
                        const bool ok = (kglob <= posq) && (kglob > posq - win);
                        const float s = ok ? sacc[mb][r] : -1e30f;
                        sacc[mb][r] = s;
                        mloc = fmaxf(mloc, s);
                    }
                }
            } else {
                #pragma unroll
                for (int mb = 0; mb < 2; ++mb) {
                    #pragma unroll
                    for (int r = 0; r < 16; ++r)
                        mloc = fmaxf(mloc, sacc[mb][r]);
                }
            }

            // T13 defer-rescale: wave-collective check; shuffles only when taken.
            if (!__all(mloc <= mrun + 8.0f)) {
                float mrow = fmaxf(mloc, __shfl_xor(mloc, 32));
                const float mnew  = fmaxf(mrun, mrow);
                const float alpha = EXP2(mrun - mnew);
                lsink *= alpha;
                plsum *= alpha;
                #pragma unroll
                for (int m = 0; m < 4; ++m) o[m] *= alpha;
                mrun = mnew;
            }

            // ---- exp in place + per-lane sum ----
            float ps = 0.f;
            #pragma unroll
            for (int mb = 0; mb < 2; ++mb) {
                #pragma unroll
                for (int r = 0; r < 16; ++r) {
                    const float e = EXP2(sacc[mb][r] - mrun);
                    sacc[mb][r] = e;
                    ps += e;
                }
            }
            plsum += ps;

            // ---- PV: P B-frags in-register via permlane32_swap; O^T += V^T·P ----
            const char* vbase = (const char*)&Vb[cur][0] + lhi5 * 16;
            #pragma unroll
            for (int kc = 0; kc < 4; ++kc) {
                const int mb   = kc >> 1;
                const int base = (kc & 1) * 8;
                unsigned a0 = pk2(sacc[mb][base + 0], sacc[mb][base + 1]);
                unsigned a1 = pk2(sacc[mb][base + 2], sacc[mb][base + 3]);
                unsigned b0 = pk2(sacc[mb][base + 4], sacc[mb][base + 5]);
                unsigned b1 = pk2(sacc[mb][base + 6], sacc[mb][base + 7]);
                asm volatile("v_permlane32_swap_b32 %0, %1" : "+v"(a0), "+v"(b0));
                asm volatile("v_permlane32_swap_b32 %0, %1" : "+v"(a1), "+v"(b1));
                u32x4 pw; pw[0] = a0; pw[1] = a1; pw[2] = b0; pw[3] = b1;
                const bf16x8 pf = __builtin_bit_cast(bf16x8, pw);
                const char* vkc = vbase + kc * 4096;
                __builtin_amdgcn_s_setprio(1);
                #pragma unroll
                for (int m = 0; m < 4; ++m) {
                    const bf16x8 vf = *reinterpret_cast<const bf16x8*>(
                        vkc + (m * 32 + l31) * 32);
                    o[m] = MFMA32(vf, pf, o[m]);
                }
                __builtin_amdgcn_s_setprio(0);
            }
        }

        __syncthreads();   // drains vmcnt (prefetch done) + protects buffers
        cur ^= 1;
    }

    // ---- epilogue: denom = own half-sum + partner half-sum + sink term ----
    const float denom = plsum + __shfl_xor(plsum, 32) + lsink;
    const float inv   = 1.0f / denom;
    const size_t obase = ((size_t)(b * Q_ + qr) * HQ_ + h) * D_;
    #pragma unroll
    for (int m = 0; m < 4; ++m) {
        #pragma unroll
        for (int rg = 0; rg < 4; ++rg) {
            const int d0 = m * 32 + rg * 8 + lhi5 * 4;
            float4v v;
            v[0] = o[m][rg * 4 + 0] * inv; v[1] = o[m][rg * 4 + 1] * inv;
            v[2] = o[m][rg * 4 + 2] * inv; v[3] = o[m][rg * 4 + 3] * inv;
            *reinterpret_cast<float4v*>(out + obase + d0) = v;
        }
    }
}

// ---------------- fallback (R2 kernel, used if ws too small) ----------------
typedef __attribute__((ext_vector_type(4))) float f32x4;
#define PP 72

__global__ __launch_bounds__(256, 2) void swa_fallback(
    const float* __restrict__ q,
    const int*   __restrict__ btab,
    const float* __restrict__ kv,
    const int*   __restrict__ seqused,
    const float* __restrict__ sinks,
    const int*   __restrict__ winp,
    float*       __restrict__ out)
{
    __shared__ __align__(16) unsigned short Klds[64 * 128];
    __shared__ __align__(16) unsigned short Vlds[64 * 128];
    __shared__ __align__(16) unsigned short Plds[4][16 * PP];

    const int tid  = threadIdx.x;
    const int lane = tid & 63;
    const int w    = tid >> 6;
    const int l15  = lane & 15;
    const int lhi  = lane >> 4;

    const int bid = blockIdx.x;
    const int qt  = bid & 7;
    const int h   = (bid >> 3) & 31;
    const int b   = bid >> 8;
    const int kh  = h >> 2;

    const int seq  = seqused[b];
    const int win  = winp[0];
    const int q0   = qt * 64;
    const int pos0 = seq - Q_ + q0;

    const int lo  = pos0 - win + 1;
    const int jt0 = (lo < 0 ? 0 : lo) & ~63;
    const int jt1 = (pos0 + 63) & ~63;

    const float SCL2 = 0.08838834764831845f * 1.4426950408889634f;

    const int    qr    = q0 + w * 16 + l15;
    const size_t qbase = ((size_t)(b * Q_ + qr) * HQ_ + h) * D_;
    bf16x8 qf[4];
    #pragma unroll
    for (int dc = 0; dc < 4; ++dc) {
        const float4v f0 = *reinterpret_cast<const float4v*>(q + qbase + dc * 32 + lhi * 8);
        const float4v f1 = *reinterpret_cast<const float4v*>(q + qbase + dc * 32 + lhi * 8 + 4);
        u32x4 p;
        p[0] = pk2(f0[0] * SCL2, f0[1] * SCL2); p[1] = pk2(f0[2] * SCL2, f0[3] * SCL2);
        p[2] = pk2(f1[0] * SCL2, f1[1] * SCL2); p[3] = pk2(f1[2] * SCL2, f1[3] * SCL2);
        qf[dc] = __builtin_bit_cast(bf16x8, p);
    }

    const int   pqmin = pos0 + w * 16;
    const int   pqmax = pqmin + 15;
    const int   posq  = pqmin + l15;
    const float sink2 = sinks[h] * 1.4426950408889634f;
    float mrun = sink2;
    float lrun = 1.0f;
    f32x4 o[8];
    #pragma unroll
    for (int g = 0; g < 8; ++g) o[g] = (f32x4){0.f, 0.f, 0.f, 0.f};

    for (int jt = jt0; jt <= jt1; jt += 64) {
        const int    blk    = btab[b * NBLK_ + (jt >> 7)];
        const size_t kgbase = (size_t)blk * (2 * BS_ * KVROW) + (size_t)(jt & 127) * KVROW + kh * D_;
        const size_t vgbase = kgbase + (size_t)BS_ * KVROW;

        __syncthreads();
        {
            const int kl = tid >> 2;
            const int cb = (tid & 3) * 64;
            const float* src = kv + kgbase + (size_t)kl * KVROW + (tid & 3) * 32;
            char* dst = (char*)Klds + kl * 256;
            #pragma unroll
            for (int i = 0; i < 4; ++i) {
                const float4v f0 = *reinterpret_cast<const float4v*>(src + i * 8);
                const float4v f1 = *reinterpret_cast<const float4v*>(src + i * 8 + 4);
                u32x4 p;
                p[0] = pk2(f0[0], f0[1]); p[1] = pk2(f0[2], f0[3]);
                p[2] = pk2(f1[0], f1[1]); p[3] = pk2(f1[2], f1[3]);
                *reinterpret_cast<u32x4*>(dst + ((cb + i * 16) ^ ((kl & 15) << 4))) = p;
            }
        }
        {
            const int db = tid & 31;
            #pragma unroll
            for (int half = 0; half < 2; ++half) {
                const int kb = (tid >> 5) + half * 8;
                const int k0 = kb * 4;
                const float* vsrc = kv + vgbase + (size_t)k0 * KVROW + db * 4;
                const float4v r0 = *reinterpret_cast<const float4v*>(vsrc);
                const float4v r1 = *reinterpret_cast<const float4v*>(vsrc + KVROW);
                const float4v r2 = *reinterpret_cast<const float4v*>(vsrc + 2 * KVROW);
                const float4v r3 = *reinterpret_cast<const float4v*>(vsrc + 3 * KVROW);
                #pragma unroll
                for (int dd = 0; dd < 4; ++dd) {
                    const int d    = db * 4 + dd;
                    const int g    = d >> 4;
                    const int slot = ((kb >> 1) & 3) * 16 + ((d & 15) ^ (g & 7));
                    const int elem = (g * 2 + (k0 >> 5)) * 512 + slot * 8 + (k0 & 7);
                    u32x2 wv;
                    wv[0] = pk2(r0[dd], r1[dd]);
                    wv[1] = pk2(r2[dd], r3[dd]);
                    *reinterpret_cast<u32x2*>(&Vlds[elem]) = wv;
                }
            }
        }
        __syncthreads();

        if (jt > pqmax || jt + 63 <= pqmin - win) continue;
        const bool edge = (jt + 63 > pqmin) || (jt <= pqmax - win);

        f32x4 sacc[4];
        #pragma unroll
        for (int g = 0; g < 4; ++g) sacc[g] = (f32x4){0.f, 0.f, 0.f, 0.f};
        #pragma unroll
        for (int g = 0; g < 4; ++g) {
            const char* krow = (const char*)Klds + (g * 16 + l15) * 256;
            const int   swz  = (l15 << 4);
            #pragma unroll
            for (int dc = 0; dc < 4; ++dc) {
                const bf16x8 a = *reinterpret_cast<const bf16x8*>(
                    krow + ((dc * 64 + lhi * 16) ^ swz));
                sacc[g] = __builtin_amdgcn_mfma_f32_16x16x32_bf16(a, qf[dc], sacc[g], 0, 0, 0);
            }
        }

        float sv[16];
        float mloc = -3e38f;
        if (edge) {
            #pragma unroll
            for (int g = 0; g < 4; ++g) {
                #pragma unroll
                for (int i = 0; i < 4; ++i) {
                    const int  kglob = jt + g * 16 + lhi * 4 + i;
                    const bool ok = (kglob <= posq) && (kglob > posq - win);
                    const float s = ok ? sacc[g][i] : -1e30f;
                    sv[g * 4 + i] = s;
                    mloc = fmaxf(mloc, s);
                }
            }
        } else {
            #pragma unroll
            for (int g = 0; g < 4; ++g) {
                #pragma unroll
                for (int i = 0; i < 4; ++i) {
                    sv[g * 4 + i] = sacc[g][i];
                    mloc = fmaxf(mloc, sacc[g][i]);
                }
            }
        }
        mloc = fmaxf(mloc, __shfl_xor(mloc, 16));
        mloc = fmaxf(mloc, __shfl_xor(mloc, 32));

        if (!__all(mloc <= mrun + 8.0f)) {
            const float mnew  = fmaxf(mrun, mloc);
            const float alpha = EXP2(mrun - mnew);
            lrun *= alpha;
            #pragma unroll
            for (int g = 0; g < 8; ++g) o[g] *= alpha;
            mrun = mnew;
        }

        float ps = 0.f;
        unsigned pw[8];
        #pragma unroll
        for (int t = 0; t < 8; ++t) {
            const float p0 = EXP2(sv[2 * t]     - mrun);
            const float p1 = EXP2(sv[2 * t + 1] - mrun);
            ps += p0 + p1;
            pw[t] = pk2(p0, p1);
        }
        ps += __shfl_xor(ps, 16);
        ps += __shfl_xor(ps, 32);
        lrun += ps;

        #pragma unroll
        for (int g = 0; g < 4; ++g) {
            u32x2 wv; wv[0] = pw[2 * g]; wv[1] = pw[2 * g + 1];
            *reinterpret_cast<u32x2*>(&Plds[w][l15 * PP + g * 16 + lhi * 4]) = wv;
        }

        #pragma unroll
        for (int kc = 0; kc < 2; ++kc) {
            const bf16x8 pf = *reinterpret_cast<const bf16x8*>(
                &Plds[w][l15 * PP + kc * 32 + lhi * 8]);
            #pragma unroll
            for (int g = 0; g < 8; ++g) {
                const bf16x8 vf = *reinterpret_cast<const bf16x8*>(
                    &Vlds[(g * 2 + kc) * 512 + (lhi * 16 + (l15 ^ (g & 7))) * 8]);
                o[g] = __builtin_amdgcn_mfma_f32_16x16x32_bf16(vf, pf, o[g], 0, 0, 0);
            }
        }
    }

    const float  inv   = 1.0f / lrun;
    const size_t obase = ((size_t)(b * Q_ + qr) * HQ_ + h) * D_;
    #pragma unroll
    for (int g = 0; g < 8; ++g) {
        float4v v;
        v[0] = o[g][0] * inv; v[1] = o[g][1] * inv;
        v[2] = o[g][2] * inv; v[3] = o[g][3] * inv;
        *reinterpret_cast<float4v*>(out + obase + g * 16 + lhi * 4) = v;
    }
}

extern "C" void kernel_launch(void* const* d_in, const int* in_sizes, int n_in,
                              void* d_out, int out_size, void* d_ws, size_t ws_size,
                              hipStream_t stream) {
    const float* q       = (const float*)d_in[0];
    const int*   btab    = (const int*)  d_in[1];
    const float* kv      = (const float*)d_in[2];
    const int*   seqused = (const int*)  d_in[3];
    const float* sinks   = (const float*)d_in[4];
    const int*   win     = (const int*)  d_in[5];
    float* out = (float*)d_out;

    const size_t wsK_elems = (size_t)NPHYS * 8 * BS_ * D_;   // 4.19M ushorts
    const size_t wsV_elems = (size_t)NPHYS * 8 * 2 * 8192;   // 4.19M ushorts
    const size_t need_bytes = (wsK_elems + wsV_elems) * 2;   // ~16.8 MB

    if (ws_size >= need_bytes) {
        unsigned short* wsK = (unsigned short*)d_ws;
        unsigned short* wsV = wsK + wsK_elems;
        swa_prepass<<<dim3(NPHYS * 8 * 2), dim3(256), 0, stream>>>(kv, wsK, wsV);
        swa_main<<<dim3(B_ * HQ_ * (Q_ / QBLK)), dim3(128), 0, stream>>>(
            q, btab, seqused, sinks, win, wsK, wsV, out);
    } else {
        swa_fallback<<<dim3(B_ * HQ_ * (Q_ / QBLK)), dim3(256), 0, stream>>>(
            q, btab, kv, seqused, sinks, win, out);
    }
}

// Round 6
// 51.850 us; speedup vs baseline: 1.1682x; 1.1682x over previous
//
#include <hip/hip_runtime.h>
#include <hip/hip_bf16.h>

// SWA with sinks: B=2, Q=512, HQ=32, HKV=8 (GQA rep=4), D=128, BS=128,
// NBLK=16, MAXK=2048, WIN=1024 (read dynamically). fp32 in/out, bf16 MFMA.
// R6: 32x32 MFMA with KEY-SPLIT waves: block = 4 waves = (2 q-halves x
// 2 key-halves), each wave = 32 q-rows x 32 keys/tile with independent
// online softmax; end-of-loop flash merge across key-halves via LDS.
// Restores 8 waves/CU (R4 occupancy) while keeping R5's halved LDS traffic.
// P stays in-register via v_permlane32_swap_b32.

#define B_    2
#define Q_    512
#define HQ_   32
#define HKV_  8
#define D_    128
#define BS_   128
#define NBLK_ 16
#define NPHYS (B_*NBLK_)
#define QBLK  64
#define KBLK  64
#define KVROW (HKV_*D_)   // 1024 floats per key position

typedef __attribute__((ext_vector_type(8)))  __bf16 bf16x8;
typedef __attribute__((ext_vector_type(16))) float  f32x16;
typedef __attribute__((ext_vector_type(4)))  float  f32x4;
typedef __attribute__((ext_vector_type(4)))  float  float4v;
typedef __attribute__((ext_vector_type(4)))  unsigned int u32x4;
typedef __attribute__((ext_vector_type(2)))  unsigned int u32x2;

#if __has_builtin(__builtin_amdgcn_exp2f)
#define EXP2(x) __builtin_amdgcn_exp2f(x)
#else
#define EXP2(x) exp2f(x)
#endif

#define MFMA32(a, b, c) __builtin_amdgcn_mfma_f32_32x32x16_bf16(a, b, c, 0, 0, 0)

// Compiler emits v_cvt_pk_bf16_f32 from paired scalar casts (m240).
__device__ __forceinline__ unsigned pk2(float a, float b) {
    union { __bf16 h[2]; unsigned u; } x;
    x.h[0] = (__bf16)a; x.h[1] = (__bf16)b;
    return x.u;
}

__device__ __forceinline__ void gld16(const void* g, void* l) {
    __builtin_amdgcn_global_load_lds(
        (const __attribute__((address_space(1))) void*)g,
        (__attribute__((address_space(3))) void*)l, 16, 0, 0);
}

// ---------------- pre-pass: fp32 KV -> bf16 ws, relayout ----------------
// wsK: [phys][kh][key 128][d 128] bf16, 256B rows XOR-swizzled byte^=(key&15)<<4
// wsV: [phys][kh][tile 2][kc 4][d 128][k16 16] bf16 (V^T, 32B rows)
// Grid mapping: bid&7 = kh so prepass writes land in the consumer XCD's L2.
__global__ __launch_bounds__(256) void swa_prepass(
    const float* __restrict__ kv,
    unsigned short* __restrict__ wsK,
    unsigned short* __restrict__ wsV)
{
    const int tid  = threadIdx.x;
    const int kh   = blockIdx.x & 7;
    const int rest = blockIdx.x >> 3;
    const int phys = rest >> 1;
    const int part = rest & 1;
    const int pk   = phys * 8 + kh;

    if (part == 0) {
        const int row = tid >> 1;
        const int dh  = (tid & 1) * 64;
        const float* src = kv + ((size_t)(phys * 2 + 0) * BS_ + row) * KVROW + kh * D_ + dh;
        char* dstrow = (char*)(wsK + ((size_t)pk * BS_ + row) * D_);
        const int swz = (row & 15) << 4;
        #pragma unroll
        for (int i = 0; i < 8; ++i) {
            const float4v f0 = *reinterpret_cast<const float4v*>(src + i * 8);
            const float4v f1 = *reinterpret_cast<const float4v*>(src + i * 8 + 4);
            u32x4 p;
            p[0] = pk2(f0[0], f0[1]); p[1] = pk2(f0[2], f0[3]);
            p[2] = pk2(f1[0], f1[1]); p[3] = pk2(f1[2], f1[3]);
            *reinterpret_cast<u32x4*>(dstrow + ((dh * 2 + i * 16) ^ swz)) = p;
        }
    } else {
        const int db  = tid & 31;    // d-block of 4
        const int kb8 = tid >> 5;    // 0..7
        #pragma unroll
        for (int tile = 0; tile < 2; ++tile) {
            unsigned short* dstt = wsV + ((size_t)pk * 2 + tile) * 8192;
            #pragma unroll
            for (int half = 0; half < 2; ++half) {
                const int kb  = kb8 + half * 8;   // 0..15
                const int k0  = kb * 4;           // key within 64-tile
                const int key = tile * 64 + k0;
                const float* vsrc = kv + ((size_t)(phys * 2 + 1) * BS_ + key) * KVROW + kh * D_ + db * 4;
                const float4v r0 = *reinterpret_cast<const float4v*>(vsrc);
                const float4v r1 = *reinterpret_cast<const float4v*>(vsrc + KVROW);
                const float4v r2 = *reinterpret_cast<const float4v*>(vsrc + 2 * KVROW);
                const float4v r3 = *reinterpret_cast<const float4v*>(vsrc + 3 * KVROW);
                #pragma unroll
                for (int dd = 0; dd < 4; ++dd) {
                    const int d    = db * 4 + dd;
                    const int elem = (k0 >> 4) * 2048 + d * 16 + (k0 & 15);
                    u32x2 wv;
                    wv[0] = pk2(r0[dd], r1[dd]);
                    wv[1] = pk2(r2[dd], r3[dd]);
                    *reinterpret_cast<u32x2*>(dstt + elem) = wv;
                }
            }
        }
    }
}

// ---------------- main kernel: 4 waves = (2 q-halves x 2 key-halves) ----------------
__global__ __launch_bounds__(256, 2) void swa_main(
    const float* __restrict__ q,
    const int*   __restrict__ btab,
    const int*   __restrict__ seqused,
    const float* __restrict__ sinks,
    const int*   __restrict__ winp,
    const unsigned short* __restrict__ wsK,
    const unsigned short* __restrict__ wsV,
    float*       __restrict__ out)
{
    __shared__ __align__(16) unsigned short Kb[2][8192];  // [key 64][d 128] swizzled
    __shared__ __align__(16) unsigned short Vb[2][8192];  // [kc 4][d 128][k16]
    __shared__ float Msc[2][32];
    __shared__ float Lsc[2][32];

    const int tid  = threadIdx.x;
    const int lane = tid & 63;
    const int w    = tid >> 6;       // wave 0..3
    const int qh   = w & 1;          // q-half
    const int kh2  = w >> 1;         // key-half
    const int l31  = lane & 31;
    const int lhi5 = lane >> 5;      // 0/1

    // kh-major block mapping: bid%8 = kh -> same-kh blocks share an XCD L2.
    const int bid   = blockIdx.x;
    const int kh    = bid & 7;
    const int inner = bid >> 3;
    const int qt    = inner & 7;
    const int hr    = (inner >> 3) & 3;
    const int b     = inner >> 5;
    const int h     = kh * 4 + hr;

    const int seq  = seqused[b];
    const int win  = winp[0];
    const int q0   = qt * QBLK;
    const int pos0 = seq - Q_ + q0;

    const int lo  = pos0 - win + 1;
    const int jt0 = (lo < 0 ? 0 : lo) & ~63;
    const int jt1 = (pos0 + QBLK - 1) & ~63;
    const int nt  = ((jt1 - jt0) >> 6) + 1;

    const float SCL2 = 0.08838834764831845f * 1.4426950408889634f;

    // ---- Q fragments: row = q0 + qh*32 + l31; qf[c][j] = Q[., c*16 + lhi5*8 + j] ----
    const int    qr    = q0 + qh * 32 + l31;
    const size_t qbase = ((size_t)(b * Q_ + qr) * HQ_ + h) * D_;
    bf16x8 qf[8];
    #pragma unroll
    for (int c = 0; c < 8; ++c) {
        const float4v f0 = *reinterpret_cast<const float4v*>(q + qbase + c * 16 + lhi5 * 8);
        const float4v f1 = *reinterpret_cast<const float4v*>(q + qbase + c * 16 + lhi5 * 8 + 4);
        u32x4 p;
        p[0] = pk2(f0[0] * SCL2, f0[1] * SCL2); p[1] = pk2(f0[2] * SCL2, f0[3] * SCL2);
        p[2] = pk2(f1[0] * SCL2, f1[1] * SCL2); p[3] = pk2(f1[2] * SCL2, f1[3] * SCL2);
        qf[c] = __builtin_bit_cast(bf16x8, p);
    }

    const int   pqmin = pos0 + qh * 32;
    const int   pqmax = pqmin + 31;
    const int   posq  = pqmin + l31;
    const float sink2 = sinks[h] * 1.4426950408889634f;
    // kh2=0 waves carry the sink term; kh2=1 start from "empty" partial.
    float mrun  = kh2 ? -1e30f : sink2;
    float lsink = kh2 ? 0.0f   : 1.0f;
    float plsum = 0.0f;
    f32x16 o[4];
    #pragma unroll
    for (int m = 0; m < 4; ++m) o[m] = (f32x16)(0.f);

    // ---- stage tile 0 (16 K-chunks + 16 V-chunks of 1KB across 4 waves) ----
    {
        const int blk = btab[b * NBLK_ + (jt0 >> 7)];
        const unsigned short* ks = wsK + ((size_t)(blk * 8 + kh) * BS_ + (jt0 & 127)) * D_;
        const unsigned short* vs = wsV + ((size_t)(blk * 8 + kh) * 2 + ((jt0 >> 6) & 1)) * 8192;
        #pragma unroll
        for (int i = 0; i < 4; ++i)
            gld16(ks + (w * 4 + i) * 512 + lane * 8, &Kb[0][(w * 4 + i) * 512]);
        #pragma unroll
        for (int i = 0; i < 4; ++i)
            gld16(vs + (w * 4 + i) * 512 + lane * 8, &Vb[0][(w * 4 + i) * 512]);
    }
    __syncthreads();

    int cur = 0;
    for (int t = 0; t < nt; ++t) {
        const int jt = jt0 + t * KBLK;
        const int kt = jt + kh2 * 32;     // this wave's 32-key base

        // ---- prefetch next tile into other buffer ----
        if (t + 1 < nt) {
            const int jn  = jt + KBLK;
            const int blk = btab[b * NBLK_ + (jn >> 7)];
            const unsigned short* ks = wsK + ((size_t)(blk * 8 + kh) * BS_ + (jn & 127)) * D_;
            const unsigned short* vs = wsV + ((size_t)(blk * 8 + kh) * 2 + ((jn >> 6) & 1)) * 8192;
            const int nb = cur ^ 1;
            #pragma unroll
            for (int i = 0; i < 4; ++i)
                gld16(ks + (w * 4 + i) * 512 + lane * 8, &Kb[nb][(w * 4 + i) * 512]);
            #pragma unroll
            for (int i = 0; i < 4; ++i)
                gld16(vs + (w * 4 + i) * 512 + lane * 8, &Vb[nb][(w * 4 + i) * 512]);
        }

        // ---- compute (skip if this wave's key-half fully masked) ----
        if (kt <= pqmax && kt + 31 > pqmin - win) {
            const bool edge = (kt + 31 > pqmin) || (kt <= pqmax - win);

            // ---- S^T = K·Q : 32 keys x 32 q, 8 d-chunks ----
            f32x16 sacc = (f32x16)(0.f);
            const char* krow = (const char*)&Kb[cur][0] + (kh2 * 32 + l31) * 256;
            const int   swz  = (l31 & 15) << 4;
            __builtin_amdgcn_s_setprio(1);
            #pragma unroll
            for (int c = 0; c < 8; ++c) {
                const bf16x8 a = *reinterpret_cast<const bf16x8*>(
                    krow + ((c * 32 + lhi5 * 16) ^ swz));
                sacc = MFMA32(a, qf[c], sacc);
            }
            __builtin_amdgcn_s_setprio(0);

            // ---- masking + per-lane local max ----
            // C layout: col q = l31, key = kt + (r&3) + 8*(r>>2) + 4*lhi5
            float mloc = -3e38f;
            if (edge) {
                #pragma unroll
                for (int r = 0; r < 16; ++r) {
                    const int  kglob = kt + (r & 3) + 8 * (r >> 2) + 4 * lhi5;
                    const bool ok = (kglob <= posq) && (kglob > posq - win);
                    const float s = ok ? sacc[r] : -1e30f;
                    sacc[r] = s;
                    mloc = fmaxf(mloc, s);
                }
            } else {
                #pragma unroll
                for (int r = 0; r < 16; ++r)
                    mloc = fmaxf(mloc, sacc[r]);
            }

            // T13 defer-rescale: wave-collective check; shuffle only when taken.
            if (!__all(mloc <= mrun + 8.0f)) {
                float mrow = fmaxf(mloc, __shfl_xor(mloc, 32));
                const float mnew  = fmaxf(mrun, mrow);
                const float alpha = EXP2(mrun - mnew);
                lsink *= alpha;
                plsum *= alpha;
                #pragma unroll
                for (int m = 0; m < 4; ++m) o[m] *= alpha;
                mrun = mnew;
            }

            // ---- exp in place + per-lane sum ----
            float ps = 0.f;
            #pragma unroll
            for (int r = 0; r < 16; ++r) {
                const float e = EXP2(sacc[r] - mrun);
                sacc[r] = e;
                ps += e;
            }
            plsum += ps;

            // ---- PV: P B-frags in-register via permlane32_swap ----
            const char* vbase = (const char*)&Vb[cur][0] + lhi5 * 16;
            #pragma unroll
            for (int kc = 0; kc < 2; ++kc) {
                const int base = kc * 8;
                unsigned a0 = pk2(sacc[base + 0], sacc[base + 1]);
                unsigned a1 = pk2(sacc[base + 2], sacc[base + 3]);
                unsigned b0 = pk2(sacc[base + 4], sacc[base + 5]);
                unsigned b1 = pk2(sacc[base + 6], sacc[base + 7]);
                asm volatile("v_permlane32_swap_b32 %0, %1" : "+v"(a0), "+v"(b0));
                asm volatile("v_permlane32_swap_b32 %0, %1" : "+v"(a1), "+v"(b1));
                u32x4 pw; pw[0] = a0; pw[1] = a1; pw[2] = b0; pw[3] = b1;
                const bf16x8 pf = __builtin_bit_cast(bf16x8, pw);
                const char* vkc = vbase + (kh2 * 2 + kc) * 4096;
                __builtin_amdgcn_s_setprio(1);
                #pragma unroll
                for (int m = 0; m < 4; ++m) {
                    const bf16x8 vf = *reinterpret_cast<const bf16x8*>(
                        vkc + (m * 32 + l31) * 32);
                    o[m] = MFMA32(vf, pf, o[m]);
                }
                __builtin_amdgcn_s_setprio(0);
            }
        }

        __syncthreads();   // drains vmcnt (prefetch done) + protects buffers
        cur ^= 1;
    }

    // ---- row total of this wave's partial denom ----
    const float lrow = plsum + __shfl_xor(plsum, 32);

    // ---- flash-merge across key-halves (reuse Kb as f32 scratch) ----
    // osc layout: [qh][lane 64][16 slots of f32x4], slot XOR-swizzled by lane&15.
    float* osc = (float*)&Kb[0][0];
    if (kh2 == 1) {
        if (lhi5 == 0) { Msc[qh][l31] = mrun; Lsc[qh][l31] = lrow; }
        float* dst = osc + qh * 4096 + lane * 64;
        #pragma unroll
        for (int m = 0; m < 4; ++m) {
            #pragma unroll
            for (int rg = 0; rg < 4; ++rg) {
                f32x4 v;
                v[0] = o[m][rg * 4 + 0]; v[1] = o[m][rg * 4 + 1];
                v[2] = o[m][rg * 4 + 2]; v[3] = o[m][rg * 4 + 3];
                *reinterpret_cast<f32x4*>(dst + (((m * 4 + rg) ^ (lane & 15)) << 2)) = v;
            }
        }
    }
    __syncthreads();

    if (kh2 == 0) {
        const float m1 = Msc[qh][l31];
        const float l1 = Lsc[qh][l31];
        const float mM = fmaxf(mrun, m1);
        const float f0 = EXP2(mrun - mM);
        const float f1 = EXP2(m1 - mM);
        const float denom = (lrow + lsink) * f0 + l1 * f1;
        const float inv   = 1.0f / denom;
        const float* src = osc + qh * 4096 + lane * 64;
        const size_t obase = ((size_t)(b * Q_ + qr) * HQ_ + h) * D_;
        #pragma unroll
        for (int m = 0; m < 4; ++m) {
            #pragma unroll
            for (int rg = 0; rg < 4; ++rg) {
                const f32x4 o1 = *reinterpret_cast<const f32x4*>(
                    src + (((m * 4 + rg) ^ (lane & 15)) << 2));
                const int d0 = m * 32 + rg * 8 + lhi5 * 4;
                float4v v;
                #pragma unroll
                for (int j = 0; j < 4; ++j)
                    v[j] = (o[m][rg * 4 + j] * f0 + o1[j] * f1) * inv;
                *reinterpret_cast<float4v*>(out + obase + d0) = v;
            }
        }
    }
}

// ---------------- fallback (R2 kernel, used if ws too small) ----------------
#define PP 72

__global__ __launch_bounds__(256, 2) void swa_fallback(
    const float* __restrict__ q,
    const int*   __restrict__ btab,
    const float* __restrict__ kv,
    const int*   __restrict__ seqused,
    const float* __restrict__ sinks,
    const int*   __restrict__ winp,
    float*       __restrict__ out)
{
    __shared__ __align__(16) unsigned short Klds[64 * 128];
    __shared__ __align__(16) unsigned short Vlds[64 * 128];
    __shared__ __align__(16) unsigned short Plds[4][16 * PP];

    const int tid  = threadIdx.x;
    const int lane = tid & 63;
    const int w    = tid >> 6;
    const int l15  = lane & 15;
    const int lhi  = lane >> 4;

    const int bid = blockIdx.x;
    const int qt  = bid & 7;
    const int h   = (bid >> 3) & 31;
    const int b   = bid >> 8;
    const int kh  = h >> 2;

    const int seq  = seqused[b];
    const int win  = winp[0];
    const int q0   = qt * 64;
    const int pos0 = seq - Q_ + q0;

    const int lo  = pos0 - win + 1;
    const int jt0 = (lo < 0 ? 0 : lo) & ~63;
    const int jt1 = (pos0 + 63) & ~63;

    const float SCL2 = 0.08838834764831845f * 1.4426950408889634f;

    const int    qr    = q0 + w * 16 + l15;
    const size_t qbase = ((size_t)(b * Q_ + qr) * HQ_ + h) * D_;
    bf16x8 qf[4];
    #pragma unroll
    for (int dc = 0; dc < 4; ++dc) {
        const float4v f0 = *reinterpret_cast<const float4v*>(q + qbase + dc * 32 + lhi * 8);
        const float4v f1 = *reinterpret_cast<const float4v*>(q + qbase + dc * 32 + lhi * 8 + 4);
        u32x4 p;
        p[0] = pk2(f0[0] * SCL2, f0[1] * SCL2); p[1] = pk2(f0[2] * SCL2, f0[3] * SCL2);
        p[2] = pk2(f1[0] * SCL2, f1[1] * SCL2); p[3] = pk2(f1[2] * SCL2, f1[3] * SCL2);
        qf[dc] = __builtin_bit_cast(bf16x8, p);
    }

    const int   pqmin = pos0 + w * 16;
    const int   pqmax = pqmin + 15;
    const int   posq  = pqmin + l15;
    const float sink2 = sinks[h] * 1.4426950408889634f;
    float mrun = sink2;
    float lrun = 1.0f;
    f32x4 o[8];
    #pragma unroll
    for (int g = 0; g < 8; ++g) o[g] = (f32x4){0.f, 0.f, 0.f, 0.f};

    for (int jt = jt0; jt <= jt1; jt += 64) {
        const int    blk    = btab[b * NBLK_ + (jt >> 7)];
        const size_t kgbase = (size_t)blk * (2 * BS_ * KVROW) + (size_t)(jt & 127) * KVROW + kh * D_;
        const size_t vgbase = kgbase + (size_t)BS_ * KVROW;

        __syncthreads();
        {
            const int kl = tid >> 2;
            const int cb = (tid & 3) * 64;
            const float* src = kv + kgbase + (size_t)kl * KVROW + (tid & 3) * 32;
            char* dst = (char*)Klds + kl * 256;
            #pragma unroll
            for (int i = 0; i < 4; ++i) {
                const float4v f0 = *reinterpret_cast<const float4v*>(src + i * 8);
                const float4v f1 = *reinterpret_cast<const float4v*>(src + i * 8 + 4);
                u32x4 p;
                p[0] = pk2(f0[0], f0[1]); p[1] = pk2(f0[2], f0[3]);
                p[2] = pk2(f1[0], f1[1]); p[3] = pk2(f1[2], f1[3]);
                *reinterpret_cast<u32x4*>(dst + ((cb + i * 16) ^ ((kl & 15) << 4))) = p;
            }
        }
        {
            const int db = tid & 31;
            #pragma unroll
            for (int half = 0; half < 2; ++half) {
                const int kb = (tid >> 5) + half * 8;
                const int k0 = kb * 4;
                const float* vsrc = kv + vgbase + (size_t)k0 * KVROW + db * 4;
                const float4v r0 = *reinterpret_cast<const float4v*>(vsrc);
                const float4v r1 = *reinterpret_cast<const float4v*>(vsrc + KVROW);
                const float4v r2 = *reinterpret_cast<const float4v*>(vsrc + 2 * KVROW);
                const float4v r3 = *reinterpret_cast<const float4v*>(vsrc + 3 * KVROW);
                #pragma unroll
                for (int dd = 0; dd < 4; ++dd) {
                    const int d    = db * 4 + dd;
                    const int g    = d >> 4;
                    const int slot = ((kb >> 1) & 3) * 16 + ((d & 15) ^ (g & 7));
                    const int elem = (g * 2 + (k0 >> 5)) * 512 + slot * 8 + (k0 & 7);
                    u32x2 wv;
                    wv[0] = pk2(r0[dd], r1[dd]);
                    wv[1] = pk2(r2[dd], r3[dd]);
                    *reinterpret_cast<u32x2*>(&Vlds[elem]) = wv;
                }
            }
        }
        __syncthreads();

        if (jt > pqmax || jt + 63 <= pqmin - win) continue;
        const bool edge = (jt + 63 > pqmin) || (jt <= pqmax - win);

        f32x4 sacc[4];
        #pragma unroll
        for (int g = 0; g < 4; ++g) sacc[g] = (f32x4){0.f, 0.f, 0.f, 0.f};
        #pragma unroll
        for (int g = 0; g < 4; ++g) {
            const char* krow = (const char*)Klds + (g * 16 + l15) * 256;
            const int   swz  = (l15 << 4);
            #pragma unroll
            for (int dc = 0; dc < 4; ++dc) {
                const bf16x8 a = *reinterpret_cast<const bf16x8*>(
                    krow + ((dc * 64 + lhi * 16) ^ swz));
                sacc[g] = __builtin_amdgcn_mfma_f32_16x16x32_bf16(a, qf[dc], sacc[g], 0, 0, 0);
            }
        }

        float sv[16];
        float mloc = -3e38f;
        if (edge) {
            #pragma unroll
            for (int g = 0; g < 4; ++g) {
                #pragma unroll
                for (int i = 0; i < 4; ++i) {
                    const int  kglob = jt + g * 16 + lhi * 4 + i;
                    const bool ok = (kglob <= posq) && (kglob > posq - win);
                    const float s = ok ? sacc[g][i] : -1e30f;
                    sv[g * 4 + i] = s;
                    mloc = fmaxf(mloc, s);
                }
            }
        } else {
            #pragma unroll
            for (int g = 0; g < 4; ++g) {
                #pragma unroll
                for (int i = 0; i < 4; ++i) {
                    sv[g * 4 + i] = sacc[g][i];
                    mloc = fmaxf(mloc, sacc[g][i]);
                }
            }
        }
        mloc = fmaxf(mloc, __shfl_xor(mloc, 16));
        mloc = fmaxf(mloc, __shfl_xor(mloc, 32));

        if (!__all(mloc <= mrun + 8.0f)) {
            const float mnew  = fmaxf(mrun, mloc);
            const float alpha = EXP2(mrun - mnew);
            lrun *= alpha;
            #pragma unroll
            for (int g = 0; g < 8; ++g) o[g] *= alpha;
            mrun = mnew;
        }

        float ps = 0.f;
        unsigned pw[8];
        #pragma unroll
        for (int t = 0; t < 8; ++t) {
            const float p0 = EXP2(sv[2 * t]     - mrun);
            const float p1 = EXP2(sv[2 * t + 1] - mrun);
            ps += p0 + p1;
            pw[t] = pk2(p0, p1);
        }
        ps += __shfl_xor(ps, 16);
        ps += __shfl_xor(ps, 32);
        lrun += ps;

        #pragma unroll
        for (int g = 0; g < 4; ++g) {
            u32x2 wv; wv[0] = pw[2 * g]; wv[1] = pw[2 * g + 1];
            *reinterpret_cast<u32x2*>(&Plds[w][l15 * PP + g * 16 + lhi * 4]) = wv;
        }

        #pragma unroll
        for (int kc = 0; kc < 2; ++kc) {
            const bf16x8 pf = *reinterpret_cast<const bf16x8*>(
                &Plds[w][l15 * PP + kc * 32 + lhi * 8]);
            #pragma unroll
            for (int g = 0; g < 8; ++g) {
                const bf16x8 vf = *reinterpret_cast<const bf16x8*>(
                    &Vlds[(g * 2 + kc) * 512 + (lhi * 16 + (l15 ^ (g & 7))) * 8]);
                o[g] = __builtin_amdgcn_mfma_f32_16x16x32_bf16(vf, pf, o[g], 0, 0, 0);
            }
        }
    }

    const float  inv   = 1.0f / lrun;
    const size_t obase = ((size_t)(b * Q_ + qr) * HQ_ + h) * D_;
    #pragma unroll
    for (int g = 0; g < 8; ++g) {
        float4v v;
        v[0] = o[g][0] * inv; v[1] = o[g][1] * inv;
        v[2] = o[g][2] * inv; v[3] = o[g][3] * inv;
        *reinterpret_cast<float4v*>(out + obase + g * 16 + lhi * 4) = v;
    }
}

extern "C" void kernel_launch(void* const* d_in, const int* in_sizes, int n_in,
                              void* d_out, int out_size, void* d_ws, size_t ws_size,
                              hipStream_t stream) {
    const float* q       = (const float*)d_in[0];
    const int*   btab    = (const int*)  d_in[1];
    const float* kv      = (const float*)d_in[2];
    const int*   seqused = (const int*)  d_in[3];
    const float* sinks   = (const float*)d_in[4];
    const int*   win     = (const int*)  d_in[5];
    float* out = (float*)d_out;

    const size_t wsK_elems = (size_t)NPHYS * 8 * BS_ * D_;   // 4.19M ushorts
    const size_t wsV_elems = (size_t)NPHYS * 8 * 2 * 8192;   // 4.19M ushorts
    const size_t need_bytes = (wsK_elems + wsV_elems) * 2;   // ~16.8 MB

    if (ws_size >= need_bytes) {
        unsigned short* wsK = (unsigned short*)d_ws;
        unsigned short* wsV = wsK + wsK_elems;
        swa_prepass<<<dim3(NPHYS * 8 * 2), dim3(256), 0, stream>>>(kv, wsK, wsV);
        swa_main<<<dim3(B_ * HQ_ * (Q_ / QBLK)), dim3(256), 0, stream>>>(
            q, btab, seqused, sinks, win, wsK, wsV, out);
    } else {
        swa_fallback<<<dim3(B_ * HQ_ * (Q_ / QBLK)), dim3(256), 0, stream>>>(
            q, btab, kv, seqused, sinks, win, out);
    }
}